// Round 1
// baseline (421.082 us; speedup 1.0000x reference)
//
#include <hip/hip_runtime.h>
#include <hip/hip_bf16.h>

// B=2, T=2048, C=2048, H=16, HD=128
#define B_  2
#define T_  2048
#define C_  2048
#define H_  16
#define HD_ 128

using bf16x8 = __attribute__((ext_vector_type(8))) __bf16;
using f32x4  = __attribute__((ext_vector_type(4))) float;

__device__ __forceinline__ unsigned short f2bs(float f) {
    __hip_bfloat16 h = __float2bfloat16(f);
    return __builtin_bit_cast(unsigned short, h);
}

// async global->LDS, 16B per lane; LDS dest = wave-uniform base + lane*16
__device__ __forceinline__ void gload_lds16(const unsigned short* g, unsigned short* l) {
    __builtin_amdgcn_global_load_lds(
        (const __attribute__((address_space(1))) unsigned int*)g,
        (__attribute__((address_space(3))) unsigned int*)l, 16, 0, 0);
}

// ---------------- merged prep: fp32->bf16 convert + 2 weight transposes ----------------
// blocks [0,8192): x convert; [8192,11264): Wqkv^T; [11264,12288): Wproj^T
__global__ __launch_bounds__(256) void k_prep(const float* __restrict__ x,
                                              unsigned short* __restrict__ XB,
                                              const float* __restrict__ Wqkv,
                                              unsigned short* __restrict__ WQKVT,
                                              const float* __restrict__ Wproj,
                                              unsigned short* __restrict__ WPROJT) {
    __shared__ unsigned short t[64][65];
    int blk = blockIdx.x;
    int tid = threadIdx.x;
    if (blk < 8192) {
        int i = blk * 256 + tid;
        float4 v = reinterpret_cast<const float4*>(x)[i];
        ushort4 o;
        o.x = f2bs(v.x); o.y = f2bs(v.y); o.z = f2bs(v.z); o.w = f2bs(v.w);
        reinterpret_cast<ushort4*>(XB)[i] = o;
        return;
    }
    const float* in;
    unsigned short* out;
    int K = 2048, N, bx, by;
    if (blk < 11264) {
        in = Wqkv; out = WQKVT; N = 6144;
        bx = (blk - 8192) % 96; by = (blk - 8192) / 96;
    } else {
        in = Wproj; out = WPROJT; N = 2048;
        bx = (blk - 11264) % 32; by = (blk - 11264) / 32;
    }
    int k0 = by * 64, n0 = bx * 64;
#pragma unroll
    for (int p = 0; p < 4; ++p) {
        int idx = p * 256 + tid;
        int r = idx >> 4, c = (idx & 15) << 2;
        float4 v = *reinterpret_cast<const float4*>(in + (long)(k0 + r) * N + n0 + c);
        t[r][c] = f2bs(v.x); t[r][c + 1] = f2bs(v.y);
        t[r][c + 2] = f2bs(v.z); t[r][c + 3] = f2bs(v.w);
    }
    __syncthreads();
#pragma unroll
    for (int p = 0; p < 4; ++p) {
        int idx = p * 256 + tid;
        int r = idx >> 4, c = (idx & 15) << 2;
        ushort4 o;
        o.x = t[c][r]; o.y = t[c + 1][r]; o.z = t[c + 2][r]; o.w = t[c + 3][r];
        *reinterpret_cast<ushort4*>(out + (long)(n0 + r) * K + k0 + c) = o;
    }
}

// ---------------- GEMM (old 128x128 structure) — used for MODE 1 (proj) only ----------------
template <int MODE>
__global__ __launch_bounds__(256, 2) void k_gemm(const unsigned short* __restrict__ A,
                                                 const unsigned short* __restrict__ Bt,
                                                 int M, int N, int K,
                                                 unsigned short* __restrict__ qkv,
                                                 float* __restrict__ out,
                                                 const float* __restrict__ bias) {
    __shared__ __align__(16) unsigned short lA[2][128 * 32];
    __shared__ __align__(16) unsigned short lB[2][128 * 32];

    int tid = threadIdx.x;
    int wave = tid >> 6, lane = tid & 63;
    int quad = lane >> 4, l16 = lane & 15;
    int wr = (wave >> 1) * 64, wc = (wave & 1) * 64;
    int m0 = blockIdx.y * 128, n0 = blockIdx.x * 128;

    int lrow = lane >> 2;
    int lcol = (lane & 3) << 3;
    const unsigned short* gA0 = A + (long)(m0 + wave * 32 + lrow) * K + lcol;
    const unsigned short* gA1 = A + (long)(m0 + wave * 32 + 16 + lrow) * K + lcol;
    const unsigned short* gB0 = Bt + (long)(n0 + wave * 32 + lrow) * K + lcol;
    const unsigned short* gB1 = Bt + (long)(n0 + wave * 32 + 16 + lrow) * K + lcol;
    int lofs0 = wave * 1024, lofs1 = wave * 1024 + 512;

    f32x4 zero = {0.f, 0.f, 0.f, 0.f};
    f32x4 acc[4][4];
#pragma unroll
    for (int i = 0; i < 4; ++i)
#pragma unroll
        for (int j = 0; j < 4; ++j) acc[i][j] = zero;

    for (int k0 = 0; k0 < K; k0 += 64) {
        __syncthreads();
#pragma unroll
        for (int h = 0; h < 2; ++h) {
            int kk = k0 + h * 32;
            gload_lds16(gA0 + kk, &lA[h][lofs0]);
            gload_lds16(gA1 + kk, &lA[h][lofs1]);
            gload_lds16(gB0 + kk, &lB[h][lofs0]);
            gload_lds16(gB1 + kk, &lB[h][lofs1]);
        }
        __syncthreads();
#pragma unroll
        for (int h = 0; h < 2; ++h) {
            bf16x8 af[4], bfr[4];
#pragma unroll
            for (int i = 0; i < 4; ++i)
                af[i] = *reinterpret_cast<const bf16x8*>(&lA[h][(wr + i * 16 + l16) * 32 + quad * 8]);
#pragma unroll
            for (int j = 0; j < 4; ++j)
                bfr[j] = *reinterpret_cast<const bf16x8*>(&lB[h][(wc + j * 16 + l16) * 32 + quad * 8]);
#pragma unroll
            for (int i = 0; i < 4; ++i)
#pragma unroll
                for (int j = 0; j < 4; ++j)
                    acc[i][j] = __builtin_amdgcn_mfma_f32_16x16x32_bf16(af[i], bfr[j], acc[i][j], 0, 0, 0);
        }
    }

#pragma unroll
    for (int i = 0; i < 4; ++i) {
#pragma unroll
        for (int j = 0; j < 4; ++j) {
#pragma unroll
            for (int r = 0; r < 4; ++r) {
                int m = m0 + wr + i * 16 + quad * 4 + r;
                int n = n0 + wc + j * 16 + l16;
                float v = acc[i][j][r];
                if (MODE == 0) {
                    int s = n >> 11, col = n & 2047;
                    int h = col >> 7, hd = col & 127;
                    int b = m >> 11, t = m & 2047;
                    long base = (long)s * (B_ * H_ * T_ * HD_);
                    if (s == 2)
                        qkv[base + ((long)(b * H_ + h) * HD_ + hd) * T_ + t] = f2bs(v);
                    else
                        qkv[base + ((long)(b * H_ + h) * T_ + t) * HD_ + hd] = f2bs(v);
                } else {
                    out[(long)m * N + n] = v + bias[n];
                }
            }
        }
    }
}

// ---------------- 256x256 quad-buffered pipelined GEMM (MODE 0: qkv) ----------------
// BK=32, 4 LDS buffers (128 KiB), 8 waves (2M x 4N), per-wave 128x64 output.
// Per K-tile: 2 phases x 16 MFMA, each phase stages 2 global_load_lds for tile t+2.
// Counted vmcnt(4) once per K-tile (never 0 in steady state) — T3+T4.
// T2: LDS XOR swizzle byte ^= ((row>>1)&3)<<4 (row stride 64B), applied on the
// pre-swizzled GLOBAL source (linear gload_lds dest) + swizzled ds_read offset.
// T5: setprio(1) around each MFMA cluster.
// Race-freedom: tile t+1 loads are strictly older than t+2's; vmcnt(4) before the
// phase-1 barrier => t+1 resident chip-wide before any wave reads it. Writes to
// buf (t+2)&3 are >=2 barrier generations after that buffer's last reads.
__global__ __launch_bounds__(512, 2) void k_gemm256(const unsigned short* __restrict__ A,
                                                    const unsigned short* __restrict__ Bt,
                                                    int M, int N, int K,
                                                    unsigned short* __restrict__ qkv) {
    __shared__ __align__(16) unsigned short lA[4][256 * 32];
    __shared__ __align__(16) unsigned short lB[4][256 * 32];

    const int tid = threadIdx.x;
    const int wave = tid >> 6, lane = tid & 63;
    const int quad = lane >> 4, l16 = lane & 15;
    const int wm = wave >> 2, wn = wave & 3;
    const int m0 = blockIdx.y * 256, n0 = blockIdx.x * 256;

    // staging: chunk (wave*2+is) covers rows chunk*16..+16 of the [256][32] tile.
    // lane L -> row chunk*16 + (L>>2), swizzled source byte col ((L&3)<<4) ^ ((L>>3&3)<<4)
    const int srow  = lane >> 2;
    const int scole = ((((lane & 3) << 4) ^ (((lane >> 3) & 3) << 4)) >> 1);
    const unsigned short* gA0 = A + (long)(m0 + wave * 32 + srow) * K + scole;
    const unsigned short* gA1 = gA0 + 16L * K;
    const unsigned short* gB0 = Bt + (long)(n0 + wave * 32 + srow) * K + scole;
    const unsigned short* gB1 = gB0 + 16L * K;
    const int ld0 = wave * 1024, ld1 = wave * 1024 + 512;

    // fragment ds_read: row base + l16, k element offset (quad ^ ((l16>>1)&3))*8
    const int kofs = ((quad ^ ((l16 >> 1) & 3)) << 3);
    const int arow = wm * 128 + l16;
    const int brow = wn * 64 + l16;

    f32x4 zero = {0.f, 0.f, 0.f, 0.f};
    f32x4 acc[8][4];
#pragma unroll
    for (int i = 0; i < 8; ++i)
#pragma unroll
        for (int j = 0; j < 4; ++j) acc[i][j] = zero;

    const int NT = K >> 5;  // 64 K-tiles of 32

    // prologue: stage tiles 0 and 1; wait for tile 0 (4 newest = tile 1 stay in flight)
    gload_lds16(gA0, &lA[0][ld0]); gload_lds16(gB0, &lB[0][ld0]);
    gload_lds16(gA1, &lA[0][ld1]); gload_lds16(gB1, &lB[0][ld1]);
    gload_lds16(gA0 + 32, &lA[1][ld0]); gload_lds16(gB0 + 32, &lB[1][ld0]);
    gload_lds16(gA1 + 32, &lA[1][ld1]); gload_lds16(gB1 + 32, &lB[1][ld1]);
    asm volatile("s_waitcnt vmcnt(4)" ::: "memory");
    asm volatile("s_barrier" ::: "memory");

#pragma unroll 4
    for (int t = 0; t < NT; ++t) {
        const int buf = t & 3, pb = (t + 2) & 3;
        const bool pf = (t + 2) < NT;
        const long ko = (long)(t + 2) << 5;

        // ---- phase 0: M-frags 0..3 x N-frags 0..3 ----
        bf16x8 af[4], bfr[4];
#pragma unroll
        for (int i = 0; i < 4; ++i)
            af[i] = *reinterpret_cast<const bf16x8*>(&lA[buf][(arow + i * 16) * 32 + kofs]);
#pragma unroll
        for (int j = 0; j < 4; ++j)
            bfr[j] = *reinterpret_cast<const bf16x8*>(&lB[buf][(brow + j * 16) * 32 + kofs]);
        if (pf) {
            gload_lds16(gA0 + ko, &lA[pb][ld0]);
            gload_lds16(gB0 + ko, &lB[pb][ld0]);
        }
        asm volatile("s_barrier" ::: "memory");
        __builtin_amdgcn_s_setprio(1);
#pragma unroll
        for (int i = 0; i < 4; ++i)
#pragma unroll
            for (int j = 0; j < 4; ++j)
                acc[i][j] = __builtin_amdgcn_mfma_f32_16x16x32_bf16(af[i], bfr[j], acc[i][j], 0, 0, 0);
        __builtin_amdgcn_s_setprio(0);
        asm volatile("s_barrier" ::: "memory");

        // ---- phase 1: M-frags 4..7 x N-frags 0..3 (B reused in regs) ----
#pragma unroll
        for (int i = 0; i < 4; ++i)
            af[i] = *reinterpret_cast<const bf16x8*>(&lA[buf][(arow + (4 + i) * 16) * 32 + kofs]);
        if (pf) {
            gload_lds16(gA1 + ko, &lA[pb][ld1]);
            gload_lds16(gB1 + ko, &lB[pb][ld1]);
            asm volatile("s_waitcnt vmcnt(4)" ::: "memory");  // tile t+1 fully resident
        } else {
            asm volatile("s_waitcnt vmcnt(0)" ::: "memory");
        }
        asm volatile("s_barrier" ::: "memory");
        __builtin_amdgcn_s_setprio(1);
#pragma unroll
        for (int i = 0; i < 4; ++i)
#pragma unroll
            for (int j = 0; j < 4; ++j)
                acc[4 + i][j] = __builtin_amdgcn_mfma_f32_16x16x32_bf16(af[i], bfr[j], acc[4 + i][j], 0, 0, 0);
        __builtin_amdgcn_s_setprio(0);
        asm volatile("s_barrier" ::: "memory");
    }

    // epilogue: qkv scatter (Q/K as [bh][T][HD], V transposed [bh][HD][T])
#pragma unroll
    for (int i = 0; i < 8; ++i) {
#pragma unroll
        for (int j = 0; j < 4; ++j) {
#pragma unroll
            for (int r = 0; r < 4; ++r) {
                int m = m0 + wm * 128 + i * 16 + quad * 4 + r;
                int n = n0 + wn * 64 + j * 16 + l16;
                float v = acc[i][j][r];
                int s = n >> 11, col = n & 2047;
                int h = col >> 7, hd = col & 127;
                int b = m >> 11, tt = m & 2047;
                long base = (long)s * (B_ * H_ * T_ * HD_);
                if (s == 2)
                    qkv[base + ((long)(b * H_ + h) * HD_ + hd) * T_ + tt] = f2bs(v);
                else
                    qkv[base + ((long)(b * H_ + h) * T_ + tt) * HD_ + hd] = f2bs(v);
            }
        }
    }
}

// ---------------- flash attention ----------------
// qkv: Q,K [bh][T][HD], V [bh][HD][T] (pre-transposed), all bf16 -> y [B*T][C] bf16
// block: 4 waves, 64 q-rows (16/wave), kv-step 64. Grid (bh=32, qtile=32), longest-first.
__global__ __launch_bounds__(256, 3) void k_attn(const unsigned short* __restrict__ qkv,
                                                 unsigned short* __restrict__ y) {
    __shared__ __align__(16) unsigned short lK[64 * 136];    // [key][hd], stride 136
    __shared__ __align__(16) unsigned short lVt[128 * 72];   // [hd][key], stride 72
    __shared__ __align__(16) unsigned short lP[4][16 * 72];  // per-wave P [qrow][key]

    int tid = threadIdx.x;
    int wave = tid >> 6, lane = tid & 63;
    int quad = lane >> 4, l16 = lane & 15;
    int bh = blockIdx.x;                          // 0..31
    int qb = ((int)gridDim.y - 1 - (int)blockIdx.y) * 64;  // heavy tiles dispatch first

    const unsigned short* Qh = qkv + (long)bh * (T_ * HD_);
    const unsigned short* Kh = qkv + (long)(B_ * H_) * T_ * HD_ + (long)bh * (T_ * HD_);
    const unsigned short* Vt = qkv + 2L * (B_ * H_) * T_ * HD_ + (long)bh * (HD_ * T_);

    bf16x8 aQ[4];
    int qrow = qb + wave * 16 + l16;
#pragma unroll
    for (int kk = 0; kk < 4; ++kk)
        aQ[kk] = *reinterpret_cast<const bf16x8*>(Qh + (long)qrow * HD_ + kk * 32 + quad * 8);

    float m_s[4], l_s[4];
    f32x4 O[8];
    f32x4 zero = {0.f, 0.f, 0.f, 0.f};
#pragma unroll
    for (int r = 0; r < 4; ++r) { m_s[r] = -1e30f; l_s[r] = 0.f; }
#pragma unroll
    for (int h = 0; h < 8; ++h) O[h] = zero;

    int qmax = qb + wave * 16 + 15;
    const float scl = 0.08838834764831845f;  // 1/sqrt(128)

    for (int kb = 0; kb < qb + 64; kb += 64) {
        __syncthreads();
#pragma unroll
        for (int p = 0; p < 4; ++p) {
            int id = p * 256 + tid;
            int r = id >> 4, cc = (id & 15) << 3;
            *reinterpret_cast<int4*>(&lK[r * 136 + cc]) =
                *reinterpret_cast<const int4*>(Kh + (long)(kb + r) * HD_ + cc);
        }
#pragma unroll
        for (int p = 0; p < 4; ++p) {
            int id = p * 256 + tid;
            int r = id >> 3, cc = (id & 7) << 3;
            *reinterpret_cast<int4*>(&lVt[r * 72 + cc]) =
                *reinterpret_cast<const int4*>(Vt + (long)r * T_ + kb + cc);
        }
        __syncthreads();
        if (kb > qmax) continue;  // wave-uniform skip; barriers stay at loop top

        f32x4 s[4];
#pragma unroll
        for (int st = 0; st < 4; ++st) s[st] = zero;
#pragma unroll
        for (int kk = 0; kk < 4; ++kk) {
#pragma unroll
            for (int st = 0; st < 4; ++st) {
                bf16x8 b = *reinterpret_cast<const bf16x8*>(
                    &lK[(st * 16 + l16) * 136 + kk * 32 + quad * 8]);
                s[st] = __builtin_amdgcn_mfma_f32_16x16x32_bf16(aQ[kk], b, s[st], 0, 0, 0);
            }
        }

        int qg = qb + wave * 16 + quad * 4;
#pragma unroll
        for (int r = 0; r < 4; ++r) {
            int q = qg + r;
            float x[4];
#pragma unroll
            for (int st = 0; st < 4; ++st)
                x[st] = (kb + st * 16 + l16 <= q) ? s[st][r] * scl : -1e30f;
            float mx = fmaxf(fmaxf(x[0], x[1]), fmaxf(x[2], x[3]));
#pragma unroll
            for (int off = 1; off < 16; off <<= 1) mx = fmaxf(mx, __shfl_xor(mx, off));
            float mn = fmaxf(m_s[r], mx);
            float al = __expf(m_s[r] - mn);
            float p[4], rs = 0.f;
#pragma unroll
            for (int st = 0; st < 4; ++st) { p[st] = __expf(x[st] - mn); rs += p[st]; }
#pragma unroll
            for (int off = 1; off < 16; off <<= 1) rs += __shfl_xor(rs, off);
            m_s[r] = mn;
            l_s[r] = l_s[r] * al + rs;
            int row = quad * 4 + r;
#pragma unroll
            for (int st = 0; st < 4; ++st)
                lP[wave][row * 72 + st * 16 + l16] = f2bs(p[st]);
#pragma unroll
            for (int h = 0; h < 8; ++h) O[h][r] *= al;
        }

#pragma unroll
        for (int kc = 0; kc < 2; ++kc) {
            bf16x8 pf = *reinterpret_cast<const bf16x8*>(
                &lP[wave][l16 * 72 + kc * 32 + quad * 8]);
#pragma unroll
            for (int h = 0; h < 8; ++h) {
                bf16x8 vf = *reinterpret_cast<const bf16x8*>(
                    &lVt[(h * 16 + l16) * 72 + kc * 32 + quad * 8]);
                O[h] = __builtin_amdgcn_mfma_f32_16x16x32_bf16(pf, vf, O[h], 0, 0, 0);
            }
        }
    }

    int b = bh >> 4, hh = bh & 15;
#pragma unroll
    for (int r = 0; r < 4; ++r) {
        int t = qb + wave * 16 + quad * 4 + r;
        float inv = 1.f / l_s[r];
#pragma unroll
        for (int h = 0; h < 8; ++h)
            y[(long)(b * T_ + t) * C_ + hh * HD_ + h * 16 + l16] = f2bs(O[h][r] * inv);
    }
}

extern "C" void kernel_launch(void* const* d_in, const int* in_sizes, int n_in,
                              void* d_out, int out_size, void* d_ws, size_t ws_size,
                              hipStream_t stream) {
    const float* x     = (const float*)d_in[0];
    // d_in[1] = causal mask, ignored (handled analytically)
    const float* Wqkv  = (const float*)d_in[2];
    const float* Wproj = (const float*)d_in[3];
    const float* bproj = (const float*)d_in[4];
    float* out = (float*)d_out;

    // workspace layout (bf16 elements); y aliases XB (XB dead after gemm1)
    unsigned short* XB     = (unsigned short*)d_ws;   // [4096][2048]  (later: y)
    unsigned short* WQKVT  = XB + 8388608;            // [6144][2048]
    unsigned short* WPROJT = WQKVT + 12582912;        // [2048][2048]
    unsigned short* QKV    = WPROJT + 4194304;        // [3][32][...]
    if (ws_size < 100663296) return;                  // 96 MB needed

    k_prep<<<12288, 256, 0, stream>>>(x, XB, Wqkv, WQKVT, Wproj, WPROJT);
    k_gemm256<<<dim3(6144 / 256, 4096 / 256), 512, 0, stream>>>(XB, WQKVT, 4096, 6144, 2048, QKV);
    k_attn<<<dim3(32, 32), 256, 0, stream>>>(QKV, XB);
    k_gemm<1><<<dim3(2048 / 128, 4096 / 128), 256, 0, stream>>>(XB, WPROJT, 4096, 2048, 2048,
                                                                nullptr, out, bproj);
}